// Round 11
// baseline (303.565 us; speedup 1.0000x reference)
//
#include <hip/hip_runtime.h>
#include <math.h>

#define B    8
#define L    4096
#define H    256
#define N2   32
#define NL   4
#define O2   512   // 2H
#define BLK  64    // scan block length
#define NBLK 64    // L/BLK
#define TVP  136   // TVc row stride (elems): 64 T + 64 Vc + 8 pad
#define MJP  72    // Mm row stride
#define UTP  72    // uT/ST LDS row stride (u16), 144B = 16B-mult
#define INP  68    // INC LDS row stride (f32), 272B = 16B-mult
#define TL2  64    // k_gemm l-tile
#define YPAD 264   // k_gemm yS row stride (u16)
#define YSZ  16896 // per-tile LDS buffer (u16): max(64*YPAD=16896, 256*64=16384)

typedef __attribute__((ext_vector_type(8))) short short8;
typedef __attribute__((ext_vector_type(4))) float f32x4;

__device__ __forceinline__ unsigned short f2bf(float f)
{
    unsigned int u = __float_as_uint(f);
    unsigned int r = (u + 0x7fffu + ((u >> 16) & 1u)) >> 16;
    return (unsigned short)r;
}

__device__ __forceinline__ float bf2f(unsigned short v)
{
    return __uint_as_float(((unsigned int)v) << 16);
}

// fast GELU: x * sigmoid(1.5957691216(x + 0.044715 x^3)) — max err ~2e-3
__device__ __forceinline__ float gelu_f(float x)
{
    float t = 1.59576912161f * fmaf(0.044715f * x * x, x, x);
    return x / (1.f + __expf(-t));
}

// ---------------- merged setup: [0,512) wcvt | [512,1536) mats | [1536,5632) tr_xu ----------------
__global__ __launch_bounds__(256) void k_setup(
    const float* __restrict__ x, const float* __restrict__ log_dt,
    const float* __restrict__ log_Ar, const float* __restrict__ A_im,
    const float* __restrict__ C_re, const float* __restrict__ C_im,
    const float* __restrict__ Dv, const float* __restrict__ Wout,
    unsigned short* __restrict__ Wb, unsigned short* __restrict__ TVc,
    unsigned short* __restrict__ Mm, float2* __restrict__ w64c,
    unsigned short* __restrict__ u)
{
    // union: tr_xu uses 8.7 KB f32 tile; mats uses 27.6 KB staging
    __shared__ __align__(16) unsigned char smem_raw[27648];
    const int bid = blockIdx.x;
    const int t = threadIdx.x;

    if (bid < 512) {
        // ---- Wout fp32 -> bf16 ----
        int idx = (bid * 256 + t) * 4;
        float4 v = *(const float4*)(Wout + idx);
        ushort4 o;
        o.x = f2bf(v.x); o.y = f2bf(v.y); o.z = f2bf(v.z); o.w = f2bf(v.w);
        *(ushort4*)(Wb + idx) = o;
    } else if (bid < 1536) {
        // ---- build per-(layer,h): T|Vc, M, w^64 — one id per block ----
        unsigned short* tvS = (unsigned short*)smem_raw;      // [64*TVP] 17408 B
        unsigned short* mmS = tvS + BLK * TVP;                // [64*MJP]  9216 B
        float* kbS = (float*)(mmS + BLK * MJP);               // [64]       256 B
        float* cS  = kbS + BLK;                               // [6*32]     768 B
        const int id = bid - 512;                             // [0, 1024)
        const int layer = id >> 8, h = id & 255;
        if (t < 32) {
            // per-n constants in double, once; broadcast via LDS
            const int n0 = t;
            const int idx = (layer * H + h) * N2 + n0;
            double dt = exp((double)log_dt[layer * H + h]);
            double Ar = -exp((double)log_Ar[idx]);
            double Ai = (double)A_im[idx];
            double dtr = dt * Ar, dti = dt * Ai;
            double er = exp(dtr);
            double dwr = er * cos(dti), dwi = er * sin(dti);
            double numr = dwr - 1.0, numi = dwi;
            double den = Ar * Ar + Ai * Ai;
            double qr0 = (numr * Ar + numi * Ai) / den;
            double qi0 = (numi * Ar - numr * Ai) / den;
            double dcr = (double)C_re[idx], dci = (double)C_im[idx];
            cS[n0]       = (float)(2.0 * (dcr * qr0 - dci * qi0));  // cr
            cS[32 + n0]  = (float)(2.0 * (dcr * qi0 + dci * qr0));  // ci
            cS[64 + n0]  = (float)dwr;                              // wr
            cS[96 + n0]  = (float)dwi;                              // wi
            double rev = dti * 0.15915494309189535;                 // dti/2pi
            cS[128 + n0] = (float)(rev - floor(rev));               // revf (frac)
            cS[160 + n0] = (float)dtr;                              // dtrf
            // w^64 in closed form (double): better than 64 serial f32 muls
            double m64 = exp(64.0 * dtr);
            double a64 = 64.0 * dti;
            w64c[(layer * H + h) * N2 + n0] =
                make_float2((float)(m64 * cos(a64)), (float)(m64 * sin(a64)));
        }
        __syncthreads();
        const int n = t & 31, dg = t >> 5;    // each thread: 8 d-values, one n
        const float cr = cS[n], ci = cS[32 + n];
        const float wr = cS[64 + n], wi = cS[96 + n];
        const float revf = cS[128 + n], dtrf = cS[160 + n];
#pragma unroll
        for (int i = 0; i < 8; ++i) {
            const int d = dg * 8 + i;
            // w^d = exp(d*dtr) * cis(2pi * frac(d*revf)) — no serial dependence
            float ph = (float)d * revf;
            ph = (ph - floorf(ph)) * 6.28318530718f;
            float mag = __expf((float)d * dtrf);
            float vr = mag * __cosf(ph);
            float vi = mag * __sinf(ph);
            float pk = fmaf(cr, vr, -(ci * vi));
            pk += __shfl_xor(pk, 1);  pk += __shfl_xor(pk, 2);
            pk += __shfl_xor(pk, 4);  pk += __shfl_xor(pk, 8);
            pk += __shfl_xor(pk, 16);
            if (n == 0) kbS[d] = pk;
            mmS[n * MJP + (63 - d)]        = f2bf(vr);
            mmS[(32 + n) * MJP + (63 - d)] = f2bf(vi);
            float v1r = vr * wr - vi * wi;            // w^{d+1}
            float v1i = vr * wi + vi * wr;
            tvS[d * TVP + 64 + n] = f2bf(fmaf(cr, v1r, -(ci * v1i)));
            tvS[d * TVP + 96 + n] = f2bf(-fmaf(cr, v1i, ci * v1r));
        }
        __syncthreads();
        {   // Toeplitz T fill: row r = t>>2, 16 cols -> two aligned short8 stores
            const int r = t >> 2, c0 = (t & 3) * 16;
            const float diag = kbS[0] + Dv[layer * H + h];
            short8 o8[2];
#pragma unroll
            for (int j = 0; j < 16; ++j) {
                int c = c0 + j;
                float val = (c > r) ? 0.f : ((c == r) ? diag : kbS[r - c]);
                o8[j >> 3][j & 7] = (short)f2bf(val);
            }
            *(short8*)&tvS[r * TVP + c0]     = o8[0];
            *(short8*)&tvS[r * TVP + c0 + 8] = o8[1];
        }
        __syncthreads();
        // coalesced blast-out (16 B/lane chunks)
        unsigned short* tv = TVc + (size_t)(layer * H + h) * BLK * TVP;
        unsigned short* mm = Mm + (size_t)(layer * H + h) * BLK * MJP;
        for (int c = t; c < (BLK * TVP) / 8; c += 256)
            *(short8*)(tv + c * 8) = *(const short8*)&tvS[c * 8];
        for (int c = t; c < (BLK * MJP) / 8; c += 256)
            *(short8*)(mm + c * 8) = *(const short8*)&mmS[c * 8];
    } else {
        // ---- transpose x (B,L,H) fp32 -> u (B,H,L) bf16 : 64l x 32h tiles, 4096 blocks ----
        float* sh = (float*)smem_raw;        // [32*68]
        const int rb = bid - 1536;           // [0, 4096)
        const int hx = rb & 7, ly = (rb >> 3) & 63, b = rb >> 9;
        const int h0 = hx * 32, l0 = ly * 64;
        const int tx = t & 7, ty = t >> 3;   // load: tx = h-quad (8x float4 = 32 h), ty = l-row (32)
        const float* xb = x + ((size_t)b * L + l0) * H + h0;
#pragma unroll
        for (int i = 0; i < 2; ++i) {
            int l = ty + i * 32;
            float4 v = *(const float4*)(xb + (size_t)l * H + tx * 4);
            sh[(tx * 4 + 0) * 68 + l] = v.x;
            sh[(tx * 4 + 1) * 68 + l] = v.y;
            sh[(tx * 4 + 2) * 68 + l] = v.z;
            sh[(tx * 4 + 3) * 68 + l] = v.w;
        }
        __syncthreads();
        // write: 32 h-rows x 64 u16 (128B contiguous per row)
        const int hh = t >> 3, cc = (t & 7) * 8;
        const float* row = &sh[hh * 68 + cc];
        short8 o8;
#pragma unroll
        for (int j = 0; j < 8; ++j) o8[j] = (short)f2bf(row[j]);
        *(short8*)(u + ((size_t)b * H + h0 + hh) * L + l0 + cc) = o8;
    }
}

// ---------------- fused scan: GEMM-A + 2-level chain + GEMM-B (row-ownership, round-8 layout) ----------------
__global__ __launch_bounds__(256) void k_scan3(
    const unsigned short* __restrict__ u, const unsigned short* __restrict__ Mm_l,
    const unsigned short* __restrict__ TVc_l, const float2* __restrict__ w64c_l,
    unsigned short* __restrict__ y)
{
    __shared__ __align__(16) unsigned short uT[BLK * UTP];   // 9.2 KB
    __shared__ __align__(16) unsigned short ST[BLK * UTP];   // 9.2 KB
    __shared__ __align__(16) float INC[BLK * INP];           // 17.4 KB
    __shared__ float2 cLd[4][32];
    const int t = threadIdx.x;
    const int wv = t >> 6, lane = t & 63;
    const int lanei = lane & 15, quad = lane >> 4;
    // XCD-sharing decomposition: h = bid&255 puts the 8 batch-siblings that read
    // the same Mm[h]/TVc[h] on the same XCD residue (256%8==0) -> mats L2-shared.
    const int h = blockIdx.x & 255, ct = blockIdx.x >> 8;    // ct = batch
    const unsigned short* ub = u + (size_t)(ct * H + h) * L;

    // early register prefetch of all mats operands (hides L2/HBM latency under
    // staging + scan; hipcc won't hoist loads across __syncthreads)
    const unsigned short* arowA = Mm_l + (size_t)h * BLK * MJP + (wv * 16 + lanei) * MJP + quad * 8;
    short8 mA[2];
    mA[0] = *(const short8*)(arowA);
    mA[1] = *(const short8*)(arowA + 32);
    const unsigned short* arowB = TVc_l + (size_t)h * BLK * TVP + (wv * 16 + lanei) * TVP + quad * 8;
    short8 tB[4];
#pragma unroll
    for (int kt = 0; kt < 4; ++kt)
        tB[kt] = *(const short8*)(arowB + kt * 32);
    const float2 w64 = w64c_l[h * N2 + (lane & 31)];

    {   // stage uT[col=blk][j] bf16 (direct copy)
        int col = t >> 2, q = t & 3;
        *(short8*)&uT[col * UTP + q * 16]     = *(const short8*)(ub + col * 64 + q * 16);
        *(short8*)&uT[col * UTP + q * 16 + 8] = *(const short8*)(ub + col * 64 + q * 16 + 8);
    }
    __syncthreads();

    // ---- GEMM-A: INC[blk][k] = sum_j M[k][j] * u[blk*64+j] ----
    {
        f32x4 acc[4];
#pragma unroll
        for (int nt = 0; nt < 4; ++nt) acc[nt] = (f32x4){0.f, 0.f, 0.f, 0.f};
#pragma unroll
        for (int kt = 0; kt < 2; ++kt) {
#pragma unroll
            for (int nt = 0; nt < 4; ++nt) {
                short8 b8 = *(const short8*)&uT[(nt * 16 + lanei) * UTP + kt * 32 + quad * 8];
                acc[nt] = __builtin_amdgcn_mfma_f32_16x16x32_bf16(mA[kt], b8, acc[nt], 0, 0, 0);
            }
        }
#pragma unroll
        for (int nt = 0; nt < 4; ++nt)
            *(f32x4*)&INC[(nt * 16 + lanei) * INP + wv * 16 + quad * 4] = acc[nt];
    }
    __syncthreads();

    // ---- chain: two-level parallel scan (each wave owns 16 blocks) ----
    const int n = lane & 31;
    float Pr[16], Pi[16];
    float w1r = 1.f, w1i = 0.f;
    if (lane < 32) {
        float sr = 0.f, si = 0.f;
        const int base = wv * 16;
#pragma unroll
        for (int k = 0; k < 16; ++k) {
            Pr[k] = sr; Pi[k] = si;
            float ir = INC[(base + k) * INP + n];
            float ii = INC[(base + k) * INP + 32 + n];
            float nr = fmaf(w64.x, sr, fmaf(-w64.y, si, ir));
            float ni = fmaf(w64.x, si, fmaf(w64.y, sr, ii));
            sr = nr; si = ni;
        }
        cLd[wv][n] = make_float2(sr, si);
        float ar = w64.x, ai = w64.y;
#pragma unroll
        for (int q = 0; q < 4; ++q) {         // w64^16
            float nr2 = ar * ar - ai * ai;
            float ni2 = 2.f * ar * ai;
            ar = nr2; ai = ni2;
        }
        w1r = ar; w1i = ai;
    }
    __syncthreads();
    if (lane < 32) {
        float Cr = 0.f, Ci = 0.f;
        for (int wp = 0; wp < wv; ++wp) {
            float2 Lw = cLd[wp][n];
            float nr = fmaf(w1r, Cr, fmaf(-w1i, Ci, Lw.x));
            float ni = fmaf(w1r, Ci, fmaf(w1i, Cr, Lw.y));
            Cr = nr; Ci = ni;
        }
        float pr = 1.f, pi = 0.f;
#pragma unroll
        for (int k = 0; k < 16; ++k) {
            int blk = wv * 16 + k;
            float Sr = fmaf(pr, Cr, fmaf(-pi, Ci, Pr[k]));
            float Si = fmaf(pr, Ci, fmaf(pi, Cr, Pi[k]));
            ST[blk * UTP + n]      = f2bf(Sr);
            ST[blk * UTP + 32 + n] = f2bf(Si);
            float npr = pr * w64.x - pi * w64.y;
            float npi = pr * w64.y + pi * w64.x;
            pr = npr; pi = npi;
        }
    }
    __syncthreads();

    // ---- GEMM-B: y = gelu(T*U + Vc*S); restage via uT -> coalesced 16B stores ----
    {
        f32x4 acc[4];
#pragma unroll
        for (int nt = 0; nt < 4; ++nt) acc[nt] = (f32x4){0.f, 0.f, 0.f, 0.f};
#pragma unroll
        for (int kt = 0; kt < 4; ++kt) {
            const unsigned short* bb = (kt < 2) ? uT : ST;
            int ko = (kt & 1) * 32 + quad * 8;
#pragma unroll
            for (int nt = 0; nt < 4; ++nt) {
                short8 b8 = *(const short8*)&bb[(nt * 16 + lanei) * UTP + ko];
                acc[nt] = __builtin_amdgcn_mfma_f32_16x16x32_bf16(tB[kt], b8, acc[nt], 0, 0, 0);
            }
        }
        __syncthreads();   // all waves done reading uT -> safe to reuse
#pragma unroll
        for (int nt = 0; nt < 4; ++nt) {
            int blk = nt * 16 + lanei;
            int i0 = wv * 16 + quad * 4;
            ushort4 o4;
            o4.x = f2bf(gelu_f(acc[nt][0]));
            o4.y = f2bf(gelu_f(acc[nt][1]));
            o4.z = f2bf(gelu_f(acc[nt][2]));
            o4.w = f2bf(gelu_f(acc[nt][3]));
            *(ushort4*)&uT[blk * UTP + i0] = o4;
        }
        __syncthreads();
        unsigned short* yb = y + (size_t)(ct * H + h) * L;
#pragma unroll
        for (int r = 0; r < 2; ++r) {
            int c = r * 256 + t;             // 512 chunks = 64 blk x 8
            int o = c >> 3, c8 = (c & 7) * 8;
            *(short8*)(yb + o * 64 + c8) = *(const short8*)&uT[o * UTP + c8];
        }
    }
}

// ---------------- MFMA GEMM + bias + GLU + residual + channel-LN: PIPELINED dual-tile ----------------
// Register-wall confirmed (R10 A/B: LDS trim 90.6->75.8 KB changed NOTHING): 512 thr x
// 256 unified regs = full VGPR pool -> 8 waves/CU, 1 block/CU. So overlap phases WITHIN
// the block instead: tile-B scatter + MFMA-B run after MFMA-A (vB global loads hidden
// under MFMA-A), residual-A loads hide under MFMA-B, residual-B loads hide under
// epilogue-A. W is read twice from L2 (cheap) in exchange for the overlap.
__global__ __launch_bounds__(512, 2) void k_gemm(
    const unsigned short* __restrict__ y, unsigned short* __restrict__ u,
    const unsigned short* __restrict__ Wb, const float* __restrict__ bo,
    const float* __restrict__ lng, const float* __restrict__ lnb,
    float* __restrict__ outp)
{
    __shared__ __align__(16) unsigned short ySA[YSZ];         // 33.8 KB
    __shared__ __align__(16) unsigned short ySB[YSZ];         // 33.8 KB
    __shared__ float bS[O2];
    __shared__ float lgS[H], lbS[H];
    __shared__ float redS[8][4][16], redQ[8][4][16];

    const int t = threadIdx.x;
    const int wv = t >> 6;
    const int lane = t & 63;
    const int lanei = lane & 15;
    const int quad = lane >> 4;
    const int idxA = blockIdx.x;             // tile A
    const int idxB = blockIdx.x + 256;       // tile B
    const int bA = idxA >> 6, l0A = (idxA & 63) * TL2;
    const int bB = idxB >> 6, l0B = (idxB & 63) * TL2;

    size_t abase[2][2];
#pragma unroll
    for (int p = 0; p < 2; ++p)
#pragma unroll
        for (int jj = 0; jj < 2; ++jj)
            abase[p][jj] = (size_t)(p * 256 + wv * 32 + jj * 16 + lanei) * H + quad * 8;

    // ---- issue BOTH tiles' y loads (8-deep MLP), scatter A only ----
    const int i = t & 7, hr = t >> 3;        // i: l-octet 0..7, hr: 0..63
    const unsigned short* ybA = y + (size_t)bA * H * L + l0A + i * 8;
    const unsigned short* ybB = y + (size_t)bB * H * L + l0B + i * 8;
    short8 vA[4], vB[4];
#pragma unroll
    for (int ps = 0; ps < 4; ++ps)
        vA[ps] = *(const short8*)(ybA + (size_t)(ps * 64 + hr) * L);
#pragma unroll
    for (int ps = 0; ps < 4; ++ps)
        vB[ps] = *(const short8*)(ybB + (size_t)(ps * 64 + hr) * L);
#pragma unroll
    for (int ps = 0; ps < 4; ++ps) {
        int h = ps * 64 + hr;
#pragma unroll
        for (int r = 0; r < 8; ++r)
            ySA[(i * 8 + r) * YPAD + (h ^ (8 * i))] = (unsigned short)vA[ps][r];
    }
    if (t < O2) bS[t] = bo[t];
    if (t < H) { lgS[t] = lng[t]; lbS[t] = lnb[t]; }
    __syncthreads();                         // ySA ready (vB stays in regs, 32 VGPR)

    f32x4 accA[2][2][4];
#pragma unroll
    for (int p = 0; p < 2; ++p)
#pragma unroll
        for (int jj = 0; jj < 2; ++jj)
#pragma unroll
            for (int nt = 0; nt < 4; ++nt)
                accA[p][jj][nt] = (f32x4){0.f, 0.f, 0.f, 0.f};

    // ---- MFMA-A (vB global loads in flight under this) ----
#pragma unroll
    for (int kt = 0; kt < 8; ++kt) {
        short8 a8[4];
#pragma unroll
        for (int q = 0; q < 4; ++q)
            a8[q] = *(const short8*)(Wb + abase[q >> 1][q & 1] + kt * 32);
        short8 bfrA[4];
#pragma unroll
        for (int nt = 0; nt < 4; ++nt) {
            int lp = nt * 16 + lanei;
            int a = (2 * nt + (lanei >> 3)) & 7;
            bfrA[nt] = *(const short8*)&ySA[lp * YPAD + ((kt * 32 + quad * 8) ^ (8 * a))];
        }
#pragma unroll
        for (int p = 0; p < 2; ++p)
#pragma unroll
            for (int jj = 0; jj < 2; ++jj)
#pragma unroll
                for (int nt = 0; nt < 4; ++nt)
                    accA[p][jj][nt] = __builtin_amdgcn_mfma_f32_16x16x32_bf16(
                        a8[p * 2 + jj], bfrA[nt], accA[p][jj][nt], 0, 0, 0);
    }

    // ---- scatter B (ySB untouched until now); issue residual-A loads ----
#pragma unroll
    for (int ps = 0; ps < 4; ++ps) {
        int h = ps * 64 + hr;
#pragma unroll
        for (int r = 0; r < 8; ++r)
            ySB[(i * 8 + r) * YPAD + (h ^ (8 * i))] = (unsigned short)vB[ps][r];
    }
    unsigned short* ubA = u + (size_t)bA * H * L + l0A;
    unsigned short* ubB = u + (size_t)bB * H * L + l0B;
    short8 rA[4];
#pragma unroll
    for (int r = 0; r < 4; ++r) {
        int c = r * 512 + t;
        int o = c >> 3, c8 = (c & 7) * 8;
        rA[r] = *(const short8*)(ubA + (size_t)o * L + c8);
    }
    __syncthreads();                         // ySB ready; all ySA reads done

    f32x4 accB[2][2][4];
#pragma unroll
    for (int p = 0; p < 2; ++p)
#pragma unroll
        for (int jj = 0; jj < 2; ++jj)
#pragma unroll
            for (int nt = 0; nt < 4; ++nt)
                accB[p][jj][nt] = (f32x4){0.f, 0.f, 0.f, 0.f};

    // ---- MFMA-B (rA loads in flight under this) ----
#pragma unroll
    for (int kt = 0; kt < 8; ++kt) {
        short8 a8[4];
#pragma unroll
        for (int q = 0; q < 4; ++q)
            a8[q] = *(const short8*)(Wb + abase[q >> 1][q & 1] + kt * 32);
        short8 bfrB[4];
#pragma unroll
        for (int nt = 0; nt < 4; ++nt) {
            int lp = nt * 16 + lanei;
            int a = (2 * nt + (lanei >> 3)) & 7;
            bfrB[nt] = *(const short8*)&ySB[lp * YPAD + ((kt * 32 + quad * 8) ^ (8 * a))];
        }
#pragma unroll
        for (int p = 0; p < 2; ++p)
#pragma unroll
            for (int jj = 0; jj < 2; ++jj)
#pragma unroll
                for (int nt = 0; nt < 4; ++nt)
                    accB[p][jj][nt] = __builtin_amdgcn_mfma_f32_16x16x32_bf16(
                        a8[p * 2 + jj], bfrB[nt], accB[p][jj][nt], 0, 0, 0);
    }

    // ---- write residual A into ySA (safe: ySA reads ended at prior barrier);
    //      issue residual-B loads (hidden under epilogue A) ----
#pragma unroll
    for (int r = 0; r < 4; ++r) {
        int c = r * 512 + t;
        int o = c >> 3, c8 = (c & 7) * 8;
        *(short8*)&ySA[o * 64 + (c8 ^ ((o & 7) << 3))] = rA[r];
    }
    short8 rB[4];
#pragma unroll
    for (int r = 0; r < 4; ++r) {
        int c = r * 512 + t;
        int o = c >> 3, c8 = (c & 7) * 8;
        rB[r] = *(const short8*)(ubB + (size_t)o * L + c8);
    }
    __syncthreads();                         // ySA residual ready; all ySB reads done

    // =========== epilogue A ===========
    {
        float psum[4] = {0.f, 0.f, 0.f, 0.f}, psq[4] = {0.f, 0.f, 0.f, 0.f};
#pragma unroll
        for (int jj = 0; jj < 2; ++jj) {
#pragma unroll
            for (int nt = 0; nt < 4; ++nt) {
                int lc = nt * 16 + lanei;
#pragma unroll
                for (int reg = 0; reg < 4; ++reg) {
                    int o = wv * 32 + jj * 16 + quad * 4 + reg;
                    float a = accA[0][jj][nt][reg] + bS[o];
                    float g = accA[1][jj][nt][reg] + bS[o + 256];
                    float glu = a / (1.f + __expf(-g));
                    float val = glu + bf2f(ySA[o * 64 + (lc ^ ((o & 7) << 3))]);
                    accA[0][jj][nt][reg] = val;
                    psum[nt] += val;
                    psq[nt] = fmaf(val, val, psq[nt]);
                }
            }
        }
#pragma unroll
        for (int nt = 0; nt < 4; ++nt) {
            psum[nt] += __shfl_xor(psum[nt], 16);
            psum[nt] += __shfl_xor(psum[nt], 32);
            psq[nt]  += __shfl_xor(psq[nt], 16);
            psq[nt]  += __shfl_xor(psq[nt], 32);
        }
        if (lane < 16) {
#pragma unroll
            for (int nt = 0; nt < 4; ++nt) {
                redS[wv][nt][lanei] = psum[nt];
                redQ[wv][nt][lanei] = psq[nt];
            }
        }
        __syncthreads();
        float mcol[4], icol[4];
#pragma unroll
        for (int nt = 0; nt < 4; ++nt) {
            float s = 0.f, q = 0.f;
#pragma unroll
            for (int w = 0; w < 8; ++w) { s += redS[w][nt][lanei]; q += redQ[w][nt][lanei]; }
            float m = s * (1.0f / 256.0f);
            float v = q * (1.0f / 256.0f) - m * m;
            mcol[nt] = m;
            icol[nt] = rsqrtf(v + 1e-5f);
        }
        if (outp == nullptr) {
#pragma unroll
            for (int jj = 0; jj < 2; ++jj) {
#pragma unroll
                for (int nt = 0; nt < 4; ++nt) {
                    int lc = nt * 16 + lanei;
#pragma unroll
                    for (int reg = 0; reg < 4; ++reg) {
                        int o = wv * 32 + jj * 16 + quad * 4 + reg;
                        float val = accA[0][jj][nt][reg];
                        float ov = (val - mcol[nt]) * icol[nt] * lgS[o] + lbS[o];
                        ySA[o * 64 + (lc ^ ((o & 7) << 3))] = f2bf(ov);
                    }
                }
            }
            __syncthreads();
#pragma unroll
            for (int r = 0; r < 4; ++r) {
                int c = r * 512 + t;
                int o = c >> 3, c8 = (c & 7) * 8;
                *(short8*)(ubA + (size_t)o * L + c8) = *(const short8*)&ySA[o * 64 + (c8 ^ ((o & 7) << 3))];
            }
        } else {
#pragma unroll
            for (int jj = 0; jj < 2; ++jj) {
#pragma unroll
                for (int nt = 0; nt < 4; ++nt) {
                    int lc = nt * 16 + lanei;
                    int o0 = wv * 32 + jj * 16 + quad * 4;
                    float4 ov;
#pragma unroll
                    for (int reg = 0; reg < 4; ++reg) {
                        int o = o0 + reg;
                        float val = accA[0][jj][nt][reg];
                        ((float*)&ov)[reg] = (val - mcol[nt]) * icol[nt] * lgS[o] + lbS[o];
                    }
                    *(float4*)(outp + ((size_t)bA * L + l0A + lc) * H + o0) = ov;
                }
            }
            __syncthreads();   // keep phase structure identical in both paths
        }
    }

    // ---- residual staging B (rB arrived under epilogue A) ----
#pragma unroll
    for (int r = 0; r < 4; ++r) {
        int c = r * 512 + t;
        int o = c >> 3, c8 = (c & 7) * 8;
        *(short8*)&ySB[o * 64 + (c8 ^ ((o & 7) << 3))] = rB[r];
    }
    __syncthreads();

    // =========== epilogue B ===========
    {
        float psum[4] = {0.f, 0.f, 0.f, 0.f}, psq[4] = {0.f, 0.f, 0.f, 0.f};
#pragma unroll
        for (int jj = 0; jj < 2; ++jj) {
#pragma unroll
            for (int nt = 0; nt < 4; ++nt) {
                int lc = nt * 16 + lanei;
#pragma unroll
                for (int reg = 0; reg < 4; ++reg) {
                    int o = wv * 32 + jj * 16 + quad * 4 + reg;
                    float a = accB[0][jj][nt][reg] + bS[o];
                    float g = accB[1][jj][nt][reg] + bS[o + 256];
                    float glu = a / (1.f + __expf(-g));
                    float val = glu + bf2f(ySB[o * 64 + (lc ^ ((o & 7) << 3))]);
                    accB[0][jj][nt][reg] = val;
                    psum[nt] += val;
                    psq[nt] = fmaf(val, val, psq[nt]);
                }
            }
        }
#pragma unroll
        for (int nt = 0; nt < 4; ++nt) {
            psum[nt] += __shfl_xor(psum[nt], 16);
            psum[nt] += __shfl_xor(psum[nt], 32);
            psq[nt]  += __shfl_xor(psq[nt], 16);
            psq[nt]  += __shfl_xor(psq[nt], 32);
        }
        if (lane < 16) {
#pragma unroll
            for (int nt = 0; nt < 4; ++nt) {
                redS[wv][nt][lanei] = psum[nt];
                redQ[wv][nt][lanei] = psq[nt];
            }
        }
        __syncthreads();
        float mcol[4], icol[4];
#pragma unroll
        for (int nt = 0; nt < 4; ++nt) {
            float s = 0.f, q = 0.f;
#pragma unroll
            for (int w = 0; w < 8; ++w) { s += redS[w][nt][lanei]; q += redQ[w][nt][lanei]; }
            float m = s * (1.0f / 256.0f);
            float v = q * (1.0f / 256.0f) - m * m;
            mcol[nt] = m;
            icol[nt] = rsqrtf(v + 1e-5f);
        }
        if (outp == nullptr) {
#pragma unroll
            for (int jj = 0; jj < 2; ++jj) {
#pragma unroll
                for (int nt = 0; nt < 4; ++nt) {
                    int lc = nt * 16 + lanei;
#pragma unroll
                    for (int reg = 0; reg < 4; ++reg) {
                        int o = wv * 32 + jj * 16 + quad * 4 + reg;
                        float val = accB[0][jj][nt][reg];
                        float ov = (val - mcol[nt]) * icol[nt] * lgS[o] + lbS[o];
                        ySB[o * 64 + (lc ^ ((o & 7) << 3))] = f2bf(ov);
                    }
                }
            }
            __syncthreads();
#pragma unroll
            for (int r = 0; r < 4; ++r) {
                int c = r * 512 + t;
                int o = c >> 3, c8 = (c & 7) * 8;
                *(short8*)(ubB + (size_t)o * L + c8) = *(const short8*)&ySB[o * 64 + (c8 ^ ((o & 7) << 3))];
            }
        } else {
#pragma unroll
            for (int jj = 0; jj < 2; ++jj) {
#pragma unroll
                for (int nt = 0; nt < 4; ++nt) {
                    int lc = nt * 16 + lanei;
                    int o0 = wv * 32 + jj * 16 + quad * 4;
                    float4 ov;
#pragma unroll
                    for (int reg = 0; reg < 4; ++reg) {
                        int o = o0 + reg;
                        float val = accB[0][jj][nt][reg];
                        ((float*)&ov)[reg] = (val - mcol[nt]) * icol[nt] * lgS[o] + lbS[o];
                    }
                    *(float4*)(outp + ((size_t)bB * L + l0B + lc) * H + o0) = ov;
                }
            }
        }
    }
}

extern "C" void kernel_launch(void* const* d_in, const int* in_sizes, int n_in,
                              void* d_out, int out_size, void* d_ws, size_t ws_size,
                              hipStream_t stream)
{
    const float* x      = (const float*)d_in[0];
    const float* log_dt = (const float*)d_in[1];
    const float* log_Ar = (const float*)d_in[2];
    const float* A_im   = (const float*)d_in[3];
    const float* C_re   = (const float*)d_in[4];
    const float* C_im   = (const float*)d_in[5];
    const float* Dv     = (const float*)d_in[6];
    const float* Wout   = (const float*)d_in[7];
    const float* bout   = (const float*)d_in[8];
    const float* lng    = (const float*)d_in[9];
    const float* lnb    = (const float*)d_in[10];
    float* out = (float*)d_out;

    unsigned short* u   = (unsigned short*)d_ws;                          // 16.8 MB
    unsigned short* Wb  = u + (size_t)B * H * L;                          // 1 MB
    unsigned short* TVc = Wb + (size_t)NL * O2 * H;                       // 17.8 MB
    unsigned short* Mm  = TVc + (size_t)NL * H * BLK * TVP;               // 9.4 MB
    float2* w64c        = (float2*)(Mm + (size_t)NL * H * BLK * MJP);     // 0.26 MB
    unsigned short* y   = (unsigned short*)(w64c + (size_t)NL * H * N2);  // 16.8 MB

    // 512 wcvt + 1024 mats + 4096 tr_xu blocks
    k_setup<<<5632, 256, 0, stream>>>(x, log_dt, log_Ar, A_im, C_re, C_im, Dv, Wout,
                                      Wb, TVc, Mm, w64c, u);
    for (int layer = 0; layer < NL; ++layer) {
        k_scan3<<<H * 8, 256, 0, stream>>>(u, Mm + (size_t)layer * H * BLK * MJP,
                                           TVc + (size_t)layer * H * BLK * TVP,
                                           w64c + (size_t)layer * H * N2, y);
        k_gemm<<<256, 512, 0, stream>>>(y, u, Wb + (size_t)layer * O2 * H,
                                        bout + layer * O2, lng + layer * H, lnb + layer * H,
                                        (layer == NL - 1) ? out : nullptr);
    }
}

// Round 12
// 273.643 us; speedup vs baseline: 1.1093x; 1.1093x over previous
//
#include <hip/hip_runtime.h>
#include <math.h>

#define B    8
#define L    4096
#define H    256
#define N2   32
#define NL   4
#define O2   512   // 2H
#define BLK  64    // scan block length
#define NBLK 64    // L/BLK
#define TVP  136   // TVc row stride (elems): 64 T + 64 Vc + 8 pad
#define MJP  72    // Mm row stride
#define UTP  72    // uT/ST LDS row stride (u16), 144B = 16B-mult
#define INP  68    // INC LDS row stride (f32), 272B = 16B-mult
#define TL2  64    // k_gemm l-tile
#define YPAD 264   // k_gemm yS row stride (u16)
#define YSZ  16896 // per-tile LDS buffer (u16): max(64*YPAD=16896, 256*64=16384)

typedef __attribute__((ext_vector_type(8))) short short8;
typedef __attribute__((ext_vector_type(4))) float f32x4;

__device__ __forceinline__ unsigned short f2bf(float f)
{
    unsigned int u = __float_as_uint(f);
    unsigned int r = (u + 0x7fffu + ((u >> 16) & 1u)) >> 16;
    return (unsigned short)r;
}

__device__ __forceinline__ float bf2f(unsigned short v)
{
    return __uint_as_float(((unsigned int)v) << 16);
}

// fast GELU: x * sigmoid(1.5957691216(x + 0.044715 x^3)) — max err ~2e-3
__device__ __forceinline__ float gelu_f(float x)
{
    float t = 1.59576912161f * fmaf(0.044715f * x * x, x, x);
    return x / (1.f + __expf(-t));
}

// ---------------- merged setup: [0,512) wcvt | [512,1536) mats | [1536,5632) tr_xu ----------------
__global__ __launch_bounds__(256) void k_setup(
    const float* __restrict__ x, const float* __restrict__ log_dt,
    const float* __restrict__ log_Ar, const float* __restrict__ A_im,
    const float* __restrict__ C_re, const float* __restrict__ C_im,
    const float* __restrict__ Dv, const float* __restrict__ Wout,
    unsigned short* __restrict__ Wb, unsigned short* __restrict__ TVc,
    unsigned short* __restrict__ Mm, float2* __restrict__ w64c,
    unsigned short* __restrict__ u)
{
    // union: tr_xu uses 8.7 KB f32 tile; mats uses 27.6 KB staging
    __shared__ __align__(16) unsigned char smem_raw[27648];
    const int bid = blockIdx.x;
    const int t = threadIdx.x;

    if (bid < 512) {
        // ---- Wout fp32 -> bf16 ----
        int idx = (bid * 256 + t) * 4;
        float4 v = *(const float4*)(Wout + idx);
        ushort4 o;
        o.x = f2bf(v.x); o.y = f2bf(v.y); o.z = f2bf(v.z); o.w = f2bf(v.w);
        *(ushort4*)(Wb + idx) = o;
    } else if (bid < 1536) {
        // ---- build per-(layer,h): T|Vc, M, w^64 — one id per block ----
        unsigned short* tvS = (unsigned short*)smem_raw;      // [64*TVP] 17408 B
        unsigned short* mmS = tvS + BLK * TVP;                // [64*MJP]  9216 B
        float* kbS = (float*)(mmS + BLK * MJP);               // [64]       256 B
        float* cS  = kbS + BLK;                               // [6*32]     768 B
        const int id = bid - 512;                             // [0, 1024)
        const int layer = id >> 8, h = id & 255;
        if (t < 32) {
            // per-n constants in double, once; broadcast via LDS
            const int n0 = t;
            const int idx = (layer * H + h) * N2 + n0;
            double dt = exp((double)log_dt[layer * H + h]);
            double Ar = -exp((double)log_Ar[idx]);
            double Ai = (double)A_im[idx];
            double dtr = dt * Ar, dti = dt * Ai;
            double er = exp(dtr);
            double dwr = er * cos(dti), dwi = er * sin(dti);
            double numr = dwr - 1.0, numi = dwi;
            double den = Ar * Ar + Ai * Ai;
            double qr0 = (numr * Ar + numi * Ai) / den;
            double qi0 = (numi * Ar - numr * Ai) / den;
            double dcr = (double)C_re[idx], dci = (double)C_im[idx];
            cS[n0]       = (float)(2.0 * (dcr * qr0 - dci * qi0));  // cr
            cS[32 + n0]  = (float)(2.0 * (dcr * qi0 + dci * qr0));  // ci
            cS[64 + n0]  = (float)dwr;                              // wr
            cS[96 + n0]  = (float)dwi;                              // wi
            double rev = dti * 0.15915494309189535;                 // dti/2pi
            cS[128 + n0] = (float)(rev - floor(rev));               // revf (frac)
            cS[160 + n0] = (float)dtr;                              // dtrf
            // w^64 in closed form (double): better than 64 serial f32 muls
            double m64 = exp(64.0 * dtr);
            double a64 = 64.0 * dti;
            w64c[(layer * H + h) * N2 + n0] =
                make_float2((float)(m64 * cos(a64)), (float)(m64 * sin(a64)));
        }
        __syncthreads();
        const int n = t & 31, dg = t >> 5;    // each thread: 8 d-values, one n
        const float cr = cS[n], ci = cS[32 + n];
        const float wr = cS[64 + n], wi = cS[96 + n];
        const float revf = cS[128 + n], dtrf = cS[160 + n];
#pragma unroll
        for (int i = 0; i < 8; ++i) {
            const int d = dg * 8 + i;
            // w^d = exp(d*dtr) * cis(2pi * frac(d*revf)) — no serial dependence
            float ph = (float)d * revf;
            ph = (ph - floorf(ph)) * 6.28318530718f;
            float mag = __expf((float)d * dtrf);
            float vr = mag * __cosf(ph);
            float vi = mag * __sinf(ph);
            float pk = fmaf(cr, vr, -(ci * vi));
            pk += __shfl_xor(pk, 1);  pk += __shfl_xor(pk, 2);
            pk += __shfl_xor(pk, 4);  pk += __shfl_xor(pk, 8);
            pk += __shfl_xor(pk, 16);
            if (n == 0) kbS[d] = pk;
            mmS[n * MJP + (63 - d)]        = f2bf(vr);
            mmS[(32 + n) * MJP + (63 - d)] = f2bf(vi);
            float v1r = vr * wr - vi * wi;            // w^{d+1}
            float v1i = vr * wi + vi * wr;
            tvS[d * TVP + 64 + n] = f2bf(fmaf(cr, v1r, -(ci * v1i)));
            tvS[d * TVP + 96 + n] = f2bf(-fmaf(cr, v1i, ci * v1r));
        }
        __syncthreads();
        {   // Toeplitz T fill: row r = t>>2, 16 cols -> two aligned short8 stores
            const int r = t >> 2, c0 = (t & 3) * 16;
            const float diag = kbS[0] + Dv[layer * H + h];
            short8 o8[2];
#pragma unroll
            for (int j = 0; j < 16; ++j) {
                int c = c0 + j;
                float val = (c > r) ? 0.f : ((c == r) ? diag : kbS[r - c]);
                o8[j >> 3][j & 7] = (short)f2bf(val);
            }
            *(short8*)&tvS[r * TVP + c0]     = o8[0];
            *(short8*)&tvS[r * TVP + c0 + 8] = o8[1];
        }
        __syncthreads();
        // coalesced blast-out (16 B/lane chunks)
        unsigned short* tv = TVc + (size_t)(layer * H + h) * BLK * TVP;
        unsigned short* mm = Mm + (size_t)(layer * H + h) * BLK * MJP;
        for (int c = t; c < (BLK * TVP) / 8; c += 256)
            *(short8*)(tv + c * 8) = *(const short8*)&tvS[c * 8];
        for (int c = t; c < (BLK * MJP) / 8; c += 256)
            *(short8*)(mm + c * 8) = *(const short8*)&mmS[c * 8];
    } else {
        // ---- transpose x (B,L,H) fp32 -> u (B,H,L) bf16 : 64l x 32h tiles, 4096 blocks ----
        float* sh = (float*)smem_raw;        // [32*68]
        const int rb = bid - 1536;           // [0, 4096)
        const int hx = rb & 7, ly = (rb >> 3) & 63, b = rb >> 9;
        const int h0 = hx * 32, l0 = ly * 64;
        const int tx = t & 7, ty = t >> 3;   // load: tx = h-quad (8x float4 = 32 h), ty = l-row (32)
        const float* xb = x + ((size_t)b * L + l0) * H + h0;
#pragma unroll
        for (int i = 0; i < 2; ++i) {
            int l = ty + i * 32;
            float4 v = *(const float4*)(xb + (size_t)l * H + tx * 4);
            sh[(tx * 4 + 0) * 68 + l] = v.x;
            sh[(tx * 4 + 1) * 68 + l] = v.y;
            sh[(tx * 4 + 2) * 68 + l] = v.z;
            sh[(tx * 4 + 3) * 68 + l] = v.w;
        }
        __syncthreads();
        // write: 32 h-rows x 64 u16 (128B contiguous per row)
        const int hh = t >> 3, cc = (t & 7) * 8;
        const float* row = &sh[hh * 68 + cc];
        short8 o8;
#pragma unroll
        for (int j = 0; j < 8; ++j) o8[j] = (short)f2bf(row[j]);
        *(short8*)(u + ((size_t)b * H + h0 + hh) * L + l0 + cc) = o8;
    }
}

// ---------------- fused scan: GEMM-A + 2-level chain + GEMM-B (row-ownership, round-8 layout) ----------------
// LDS cut 36.8 -> 27.6 KB: ST aliases INC (all INC reads finish at the barrier
// after scan phase 1; ST is written only in phase 2 and fits in INC's 17.4 KB).
// 4 -> 5 blocks/CU: +25% TLP for the latency-dominated 7-barrier phase chain.
__global__ __launch_bounds__(256) void k_scan3(
    const unsigned short* __restrict__ u, const unsigned short* __restrict__ Mm_l,
    const unsigned short* __restrict__ TVc_l, const float2* __restrict__ w64c_l,
    unsigned short* __restrict__ y)
{
    __shared__ __align__(16) unsigned short uT[BLK * UTP];   // 9.2 KB
    __shared__ __align__(16) float INC[BLK * INP];           // 17.4 KB (ST aliases this)
    __shared__ float2 cLd[4][32];
    unsigned short* ST = (unsigned short*)INC;               // alias: phase-2 only
    const int t = threadIdx.x;
    const int wv = t >> 6, lane = t & 63;
    const int lanei = lane & 15, quad = lane >> 4;
    // XCD-sharing decomposition: h = bid&255 puts the 8 batch-siblings that read
    // the same Mm[h]/TVc[h] on the same XCD residue (256%8==0) -> mats L2-shared.
    const int h = blockIdx.x & 255, ct = blockIdx.x >> 8;    // ct = batch
    const unsigned short* ub = u + (size_t)(ct * H + h) * L;

    // early register prefetch of all mats operands (hides L2/HBM latency under
    // staging + scan; hipcc won't hoist loads across __syncthreads)
    const unsigned short* arowA = Mm_l + (size_t)h * BLK * MJP + (wv * 16 + lanei) * MJP + quad * 8;
    short8 mA[2];
    mA[0] = *(const short8*)(arowA);
    mA[1] = *(const short8*)(arowA + 32);
    const unsigned short* arowB = TVc_l + (size_t)h * BLK * TVP + (wv * 16 + lanei) * TVP + quad * 8;
    short8 tB[4];
#pragma unroll
    for (int kt = 0; kt < 4; ++kt)
        tB[kt] = *(const short8*)(arowB + kt * 32);
    const float2 w64 = w64c_l[h * N2 + (lane & 31)];

    {   // stage uT[col=blk][j] bf16 (direct copy)
        int col = t >> 2, q = t & 3;
        *(short8*)&uT[col * UTP + q * 16]     = *(const short8*)(ub + col * 64 + q * 16);
        *(short8*)&uT[col * UTP + q * 16 + 8] = *(const short8*)(ub + col * 64 + q * 16 + 8);
    }
    __syncthreads();

    // ---- GEMM-A: INC[blk][k] = sum_j M[k][j] * u[blk*64+j] ----
    {
        f32x4 acc[4];
#pragma unroll
        for (int nt = 0; nt < 4; ++nt) acc[nt] = (f32x4){0.f, 0.f, 0.f, 0.f};
#pragma unroll
        for (int kt = 0; kt < 2; ++kt) {
#pragma unroll
            for (int nt = 0; nt < 4; ++nt) {
                short8 b8 = *(const short8*)&uT[(nt * 16 + lanei) * UTP + kt * 32 + quad * 8];
                acc[nt] = __builtin_amdgcn_mfma_f32_16x16x32_bf16(mA[kt], b8, acc[nt], 0, 0, 0);
            }
        }
#pragma unroll
        for (int nt = 0; nt < 4; ++nt)
            *(f32x4*)&INC[(nt * 16 + lanei) * INP + wv * 16 + quad * 4] = acc[nt];
    }
    __syncthreads();

    // ---- chain: two-level parallel scan (each wave owns 16 blocks) ----
    const int n = lane & 31;
    float Pr[16], Pi[16];
    float w1r = 1.f, w1i = 0.f;
    if (lane < 32) {
        float sr = 0.f, si = 0.f;
        const int base = wv * 16;
#pragma unroll
        for (int k = 0; k < 16; ++k) {
            Pr[k] = sr; Pi[k] = si;
            float ir = INC[(base + k) * INP + n];
            float ii = INC[(base + k) * INP + 32 + n];
            float nr = fmaf(w64.x, sr, fmaf(-w64.y, si, ir));
            float ni = fmaf(w64.x, si, fmaf(w64.y, sr, ii));
            sr = nr; si = ni;
        }
        cLd[wv][n] = make_float2(sr, si);
        float ar = w64.x, ai = w64.y;
#pragma unroll
        for (int q = 0; q < 4; ++q) {         // w64^16
            float nr2 = ar * ar - ai * ai;
            float ni2 = 2.f * ar * ai;
            ar = nr2; ai = ni2;
        }
        w1r = ar; w1i = ai;
    }
    __syncthreads();                          // all INC reads complete here
    if (lane < 32) {
        float Cr = 0.f, Ci = 0.f;
        for (int wp = 0; wp < wv; ++wp) {
            float2 Lw = cLd[wp][n];
            float nr = fmaf(w1r, Cr, fmaf(-w1i, Ci, Lw.x));
            float ni = fmaf(w1r, Ci, fmaf(w1i, Cr, Lw.y));
            Cr = nr; Ci = ni;
        }
        float pr = 1.f, pi = 0.f;
#pragma unroll
        for (int k = 0; k < 16; ++k) {        // ST writes clobber INC: safe, INC dead
            int blk = wv * 16 + k;
            float Sr = fmaf(pr, Cr, fmaf(-pi, Ci, Pr[k]));
            float Si = fmaf(pr, Ci, fmaf(pi, Cr, Pi[k]));
            ST[blk * UTP + n]      = f2bf(Sr);
            ST[blk * UTP + 32 + n] = f2bf(Si);
            float npr = pr * w64.x - pi * w64.y;
            float npi = pr * w64.y + pi * w64.x;
            pr = npr; pi = npi;
        }
    }
    __syncthreads();

    // ---- GEMM-B: y = gelu(T*U + Vc*S); restage via uT -> coalesced 16B stores ----
    {
        f32x4 acc[4];
#pragma unroll
        for (int nt = 0; nt < 4; ++nt) acc[nt] = (f32x4){0.f, 0.f, 0.f, 0.f};
#pragma unroll
        for (int kt = 0; kt < 4; ++kt) {
            const unsigned short* bb = (kt < 2) ? uT : ST;
            int ko = (kt & 1) * 32 + quad * 8;
#pragma unroll
            for (int nt = 0; nt < 4; ++nt) {
                short8 b8 = *(const short8*)&bb[(nt * 16 + lanei) * UTP + ko];
                acc[nt] = __builtin_amdgcn_mfma_f32_16x16x32_bf16(tB[kt], b8, acc[nt], 0, 0, 0);
            }
        }
        __syncthreads();   // all waves done reading uT -> safe to reuse
#pragma unroll
        for (int nt = 0; nt < 4; ++nt) {
            int blk = nt * 16 + lanei;
            int i0 = wv * 16 + quad * 4;
            ushort4 o4;
            o4.x = f2bf(gelu_f(acc[nt][0]));
            o4.y = f2bf(gelu_f(acc[nt][1]));
            o4.z = f2bf(gelu_f(acc[nt][2]));
            o4.w = f2bf(gelu_f(acc[nt][3]));
            *(ushort4*)&uT[blk * UTP + i0] = o4;
        }
        __syncthreads();
        unsigned short* yb = y + (size_t)(ct * H + h) * L;
#pragma unroll
        for (int r = 0; r < 2; ++r) {
            int c = r * 256 + t;             // 512 chunks = 64 blk x 8
            int o = c >> 3, c8 = (c & 7) * 8;
            *(short8*)(yb + o * 64 + c8) = *(const short8*)&uT[o * UTP + c8];
        }
    }
}

// ---------------- MFMA GEMM + bias + GLU + residual + channel-LN: dual-tile (R8 joint form) ----------------
// MEASURED-BEST structure (272.2us total). Joint MFMA loop is the key: each W
// fragment feeds 32 interleaved A/B MFMAs (two independent dep streams = ILP).
// R11's split-pipeline variant regressed +7.8us/dispatch — do not re-split.
// Register-wall: 512thr x 256 unified regs = full pool -> 1 block/CU (LDS trim
// to 75.8KB proven null in R10).
__global__ __launch_bounds__(512, 2) void k_gemm(
    const unsigned short* __restrict__ y, unsigned short* __restrict__ u,
    const unsigned short* __restrict__ Wb, const float* __restrict__ bo,
    const float* __restrict__ lng, const float* __restrict__ lnb,
    float* __restrict__ outp)
{
    __shared__ __align__(16) unsigned short ySA[YSZ];         // 33.8 KB
    __shared__ __align__(16) unsigned short ySB[YSZ];         // 33.8 KB
    __shared__ float bS[O2];
    __shared__ float lgS[H], lbS[H];
    __shared__ float redS[8][4][16], redQ[8][4][16];

    const int t = threadIdx.x;
    const int wv = t >> 6;
    const int lane = t & 63;
    const int lanei = lane & 15;
    const int quad = lane >> 4;
    const int idxA = blockIdx.x;             // tile A
    const int idxB = blockIdx.x + 256;       // tile B
    const int bA = idxA >> 6, l0A = (idxA & 63) * TL2;
    const int bB = idxB >> 6, l0B = (idxB & 63) * TL2;

    size_t abase[2][2];
#pragma unroll
    for (int p = 0; p < 2; ++p)
#pragma unroll
        for (int jj = 0; jj < 2; ++jj)
            abase[p][jj] = (size_t)(p * 256 + wv * 32 + jj * 16 + lanei) * H + quad * 8;

    {   // stage BOTH y tiles (256h x 64l bf16 each) -> ySx[l][h ^ 8*(l>>3)] (swizzled)
        const int i = t & 7, hr = t >> 3;    // i: l-octet 0..7, hr: 0..63
        const unsigned short* ybA = y + (size_t)bA * H * L + l0A + i * 8;
        const unsigned short* ybB = y + (size_t)bB * H * L + l0B + i * 8;
        short8 vA[4], vB[4];
#pragma unroll
        for (int ps = 0; ps < 4; ++ps)
            vA[ps] = *(const short8*)(ybA + (size_t)(ps * 64 + hr) * L);
#pragma unroll
        for (int ps = 0; ps < 4; ++ps)
            vB[ps] = *(const short8*)(ybB + (size_t)(ps * 64 + hr) * L);
#pragma unroll
        for (int ps = 0; ps < 4; ++ps) {
            int h = ps * 64 + hr;
#pragma unroll
            for (int r = 0; r < 8; ++r)
                ySA[(i * 8 + r) * YPAD + (h ^ (8 * i))] = (unsigned short)vA[ps][r];
        }
#pragma unroll
        for (int ps = 0; ps < 4; ++ps) {
            int h = ps * 64 + hr;
#pragma unroll
            for (int r = 0; r < 8; ++r)
                ySB[(i * 8 + r) * YPAD + (h ^ (8 * i))] = (unsigned short)vB[ps][r];
        }
        if (t < O2) bS[t] = bo[t];
        if (t < H) { lgS[t] = lng[t]; lbS[t] = lnb[t]; }
    }
    __syncthreads();

    f32x4 accA[2][2][4], accB[2][2][4];
#pragma unroll
    for (int p = 0; p < 2; ++p)
#pragma unroll
        for (int jj = 0; jj < 2; ++jj)
#pragma unroll
            for (int nt = 0; nt < 4; ++nt) {
                accA[p][jj][nt] = (f32x4){0.f, 0.f, 0.f, 0.f};
                accB[p][jj][nt] = (f32x4){0.f, 0.f, 0.f, 0.f};
            }

    // joint MFMA loop: one W-fragment batch per kt drives both tiles
#pragma unroll
    for (int kt = 0; kt < 8; ++kt) {
        short8 a8[4];
#pragma unroll
        for (int q = 0; q < 4; ++q)
            a8[q] = *(const short8*)(Wb + abase[q >> 1][q & 1] + kt * 32);
        short8 bfrA[4], bfrB[4];
#pragma unroll
        for (int nt = 0; nt < 4; ++nt) {
            int lp = nt * 16 + lanei;
            int a = (2 * nt + (lanei >> 3)) & 7;
            int off = lp * YPAD + ((kt * 32 + quad * 8) ^ (8 * a));
            bfrA[nt] = *(const short8*)&ySA[off];
            bfrB[nt] = *(const short8*)&ySB[off];
        }
#pragma unroll
        for (int p = 0; p < 2; ++p)
#pragma unroll
            for (int jj = 0; jj < 2; ++jj) {
#pragma unroll
                for (int nt = 0; nt < 4; ++nt) {
                    accA[p][jj][nt] = __builtin_amdgcn_mfma_f32_16x16x32_bf16(
                        a8[p * 2 + jj], bfrA[nt], accA[p][jj][nt], 0, 0, 0);
                    accB[p][jj][nt] = __builtin_amdgcn_mfma_f32_16x16x32_bf16(
                        a8[p * 2 + jj], bfrB[nt], accB[p][jj][nt], 0, 0, 0);
                }
            }
    }

    // ---- residual staging A (issue loads, then LDS write after barrier) ----
    // residual layout: yS[o*64 + (col ^ ((o&7)<<3))] — stride 64, XOR swizzle
    unsigned short* ubA = u + (size_t)bA * H * L + l0A;
    unsigned short* ubB = u + (size_t)bB * H * L + l0B;
    short8 rA[4];
#pragma unroll
    for (int r = 0; r < 4; ++r) {
        int c = r * 512 + t;
        int o = c >> 3, c8 = (c & 7) * 8;
        rA[r] = *(const short8*)(ubA + (size_t)o * L + c8);
    }
    __syncthreads();   // all waves done reading ySA/ySB -> safe to reuse
#pragma unroll
    for (int r = 0; r < 4; ++r) {
        int c = r * 512 + t;
        int o = c >> 3, c8 = (c & 7) * 8;
        *(short8*)&ySA[o * 64 + (c8 ^ ((o & 7) << 3))] = rA[r];
    }
    // issue residual B loads now: in flight across epilogue A
    short8 rB[4];
#pragma unroll
    for (int r = 0; r < 4; ++r) {
        int c = r * 512 + t;
        int o = c >> 3, c8 = (c & 7) * 8;
        rB[r] = *(const short8*)(ubB + (size_t)o * L + c8);
    }
    __syncthreads();

    // =========== epilogue A ===========
    {
        float psum[4] = {0.f, 0.f, 0.f, 0.f}, psq[4] = {0.f, 0.f, 0.f, 0.f};
#pragma unroll
        for (int jj = 0; jj < 2; ++jj) {
#pragma unroll
            for (int nt = 0; nt < 4; ++nt) {
                int lc = nt * 16 + lanei;
#pragma unroll
                for (int reg = 0; reg < 4; ++reg) {
                    int o = wv * 32 + jj * 16 + quad * 4 + reg;
                    float a = accA[0][jj][nt][reg] + bS[o];
                    float g = accA[1][jj][nt][reg] + bS[o + 256];
                    float glu = a / (1.f + __expf(-g));
                    float val = glu + bf2f(ySA[o * 64 + (lc ^ ((o & 7) << 3))]);
                    accA[0][jj][nt][reg] = val;
                    psum[nt] += val;
                    psq[nt] = fmaf(val, val, psq[nt]);
                }
            }
        }
#pragma unroll
        for (int nt = 0; nt < 4; ++nt) {
            psum[nt] += __shfl_xor(psum[nt], 16);
            psum[nt] += __shfl_xor(psum[nt], 32);
            psq[nt]  += __shfl_xor(psq[nt], 16);
            psq[nt]  += __shfl_xor(psq[nt], 32);
        }
        if (lane < 16) {
#pragma unroll
            for (int nt = 0; nt < 4; ++nt) {
                redS[wv][nt][lanei] = psum[nt];
                redQ[wv][nt][lanei] = psq[nt];
            }
        }
        __syncthreads();
        float mcol[4], icol[4];
#pragma unroll
        for (int nt = 0; nt < 4; ++nt) {
            float s = 0.f, q = 0.f;
#pragma unroll
            for (int w = 0; w < 8; ++w) { s += redS[w][nt][lanei]; q += redQ[w][nt][lanei]; }
            float m = s * (1.0f / 256.0f);
            float v = q * (1.0f / 256.0f) - m * m;
            mcol[nt] = m;
            icol[nt] = rsqrtf(v + 1e-5f);
        }
        if (outp == nullptr) {
#pragma unroll
            for (int jj = 0; jj < 2; ++jj) {
#pragma unroll
                for (int nt = 0; nt < 4; ++nt) {
                    int lc = nt * 16 + lanei;
#pragma unroll
                    for (int reg = 0; reg < 4; ++reg) {
                        int o = wv * 32 + jj * 16 + quad * 4 + reg;
                        float val = accA[0][jj][nt][reg];
                        float ov = (val - mcol[nt]) * icol[nt] * lgS[o] + lbS[o];
                        ySA[o * 64 + (lc ^ ((o & 7) << 3))] = f2bf(ov);
                    }
                }
            }
            __syncthreads();
#pragma unroll
            for (int r = 0; r < 4; ++r) {
                int c = r * 512 + t;
                int o = c >> 3, c8 = (c & 7) * 8;
                *(short8*)(ubA + (size_t)o * L + c8) = *(const short8*)&ySA[o * 64 + (c8 ^ ((o & 7) << 3))];
            }
        } else {
#pragma unroll
            for (int jj = 0; jj < 2; ++jj) {
#pragma unroll
                for (int nt = 0; nt < 4; ++nt) {
                    int lc = nt * 16 + lanei;
                    int o0 = wv * 32 + jj * 16 + quad * 4;
                    float4 ov;
#pragma unroll
                    for (int reg = 0; reg < 4; ++reg) {
                        int o = o0 + reg;
                        float val = accA[0][jj][nt][reg];
                        ((float*)&ov)[reg] = (val - mcol[nt]) * icol[nt] * lgS[o] + lbS[o];
                    }
                    *(float4*)(outp + ((size_t)bA * L + l0A + lc) * H + o0) = ov;
                }
            }
            __syncthreads();   // keep phase structure identical in both paths
        }
    }

    // ---- residual staging B ----
#pragma unroll
    for (int r = 0; r < 4; ++r) {
        int c = r * 512 + t;
        int o = c >> 3, c8 = (c & 7) * 8;
        *(short8*)&ySB[o * 64 + (c8 ^ ((o & 7) << 3))] = rB[r];
    }
    __syncthreads();

    // =========== epilogue B ===========
    {
        float psum[4] = {0.f, 0.f, 0.f, 0.f}, psq[4] = {0.f, 0.f, 0.f, 0.f};
#pragma unroll
        for (int jj = 0; jj < 2; ++jj) {
#pragma unroll
            for (int nt = 0; nt < 4; ++nt) {
                int lc = nt * 16 + lanei;
#pragma unroll
                for (int reg = 0; reg < 4; ++reg) {
                    int o = wv * 32 + jj * 16 + quad * 4 + reg;
                    float a = accB[0][jj][nt][reg] + bS[o];
                    float g = accB[1][jj][nt][reg] + bS[o + 256];
                    float glu = a / (1.f + __expf(-g));
                    float val = glu + bf2f(ySB[o * 64 + (lc ^ ((o & 7) << 3))]);
                    accB[0][jj][nt][reg] = val;
                    psum[nt] += val;
                    psq[nt] = fmaf(val, val, psq[nt]);
                }
            }
        }
#pragma unroll
        for (int nt = 0; nt < 4; ++nt) {
            psum[nt] += __shfl_xor(psum[nt], 16);
            psum[nt] += __shfl_xor(psum[nt], 32);
            psq[nt]  += __shfl_xor(psq[nt], 16);
            psq[nt]  += __shfl_xor(psq[nt], 32);
        }
        if (lane < 16) {
#pragma unroll
            for (int nt = 0; nt < 4; ++nt) {
                redS[wv][nt][lanei] = psum[nt];
                redQ[wv][nt][lanei] = psq[nt];
            }
        }
        __syncthreads();
        float mcol[4], icol[4];
#pragma unroll
        for (int nt = 0; nt < 4; ++nt) {
            float s = 0.f, q = 0.f;
#pragma unroll
            for (int w = 0; w < 8; ++w) { s += redS[w][nt][lanei]; q += redQ[w][nt][lanei]; }
            float m = s * (1.0f / 256.0f);
            float v = q * (1.0f / 256.0f) - m * m;
            mcol[nt] = m;
            icol[nt] = rsqrtf(v + 1e-5f);
        }
        if (outp == nullptr) {
#pragma unroll
            for (int jj = 0; jj < 2; ++jj) {
#pragma unroll
                for (int nt = 0; nt < 4; ++nt) {
                    int lc = nt * 16 + lanei;
#pragma unroll
                    for (int reg = 0; reg < 4; ++reg) {
                        int o = wv * 32 + jj * 16 + quad * 4 + reg;
                        float val = accB[0][jj][nt][reg];
                        float ov = (val - mcol[nt]) * icol[nt] * lgS[o] + lbS[o];
                        ySB[o * 64 + (lc ^ ((o & 7) << 3))] = f2bf(ov);
                    }
                }
            }
            __syncthreads();
#pragma unroll
            for (int r = 0; r < 4; ++r) {
                int c = r * 512 + t;
                int o = c >> 3, c8 = (c & 7) * 8;
                *(short8*)(ubB + (size_t)o * L + c8) = *(const short8*)&ySB[o * 64 + (c8 ^ ((o & 7) << 3))];
            }
        } else {
#pragma unroll
            for (int jj = 0; jj < 2; ++jj) {
#pragma unroll
                for (int nt = 0; nt < 4; ++nt) {
                    int lc = nt * 16 + lanei;
                    int o0 = wv * 32 + jj * 16 + quad * 4;
                    float4 ov;
#pragma unroll
                    for (int reg = 0; reg < 4; ++reg) {
                        int o = o0 + reg;
                        float val = accB[0][jj][nt][reg];
                        ((float*)&ov)[reg] = (val - mcol[nt]) * icol[nt] * lgS[o] + lbS[o];
                    }
                    *(float4*)(outp + ((size_t)bB * L + l0B + lc) * H + o0) = ov;
                }
            }
        }
    }
}

extern "C" void kernel_launch(void* const* d_in, const int* in_sizes, int n_in,
                              void* d_out, int out_size, void* d_ws, size_t ws_size,
                              hipStream_t stream)
{
    const float* x      = (const float*)d_in[0];
    const float* log_dt = (const float*)d_in[1];
    const float* log_Ar = (const float*)d_in[2];
    const float* A_im   = (const float*)d_in[3];
    const float* C_re   = (const float*)d_in[4];
    const float* C_im   = (const float*)d_in[5];
    const float* Dv     = (const float*)d_in[6];
    const float* Wout   = (const float*)d_in[7];
    const float* bout   = (const float*)d_in[8];
    const float* lng    = (const float*)d_in[9];
    const float* lnb    = (const float*)d_in[10];
    float* out = (float*)d_out;

    unsigned short* u   = (unsigned short*)d_ws;                          // 16.8 MB
    unsigned short* Wb  = u + (size_t)B * H * L;                          // 1 MB
    unsigned short* TVc = Wb + (size_t)NL * O2 * H;                       // 17.8 MB
    unsigned short* Mm  = TVc + (size_t)NL * H * BLK * TVP;               // 9.4 MB
    float2* w64c        = (float2*)(Mm + (size_t)NL * H * BLK * MJP);     // 0.26 MB
    unsigned short* y   = (unsigned short*)(w64c + (size_t)NL * H * N2);  // 16.8 MB

    // 512 wcvt + 1024 mats + 4096 tr_xu blocks
    k_setup<<<5632, 256, 0, stream>>>(x, log_dt, log_Ar, A_im, C_re, C_im, Dv, Wout,
                                      Wb, TVc, Mm, w64c, u);
    for (int layer = 0; layer < NL; ++layer) {
        k_scan3<<<H * 8, 256, 0, stream>>>(u, Mm + (size_t)layer * H * BLK * MJP,
                                           TVc + (size_t)layer * H * BLK * TVP,
                                           w64c + (size_t)layer * H * N2, y);
        k_gemm<<<256, 512, 0, stream>>>(y, u, Wb + (size_t)layer * O2 * H,
                                        bout + layer * O2, lng + layer * H, lnb + layer * H,
                                        (layer == NL - 1) ? out : nullptr);
    }
}